// Round 6
// baseline (356.710 us; speedup 1.0000x reference)
//
#include <hip/hip_runtime.h>

// MSE-sum loss: out[0] = 0.5 * sum((a[i]-b[i])^2), n = 40e6 fp32 per input.
// R5: nontemporal loads broke the ~2.9 TB/s L3-arbitration plateau
// (stage1 ~110 -> ~85 us). R6: deepen MLP — 8 float4 per array per thread
// (16 straight-line nt loads, 64 KB per block), one-shot dispatch,
// two-stage reduction via d_ws.

typedef float fvec4 __attribute__((ext_vector_type(4)));

__global__ __launch_bounds__(256) void mse_stage1(const fvec4* __restrict__ a4,
                                                  const fvec4* __restrict__ b4,
                                                  float* __restrict__ partial,
                                                  long n4) {
    const int t = threadIdx.x;
    const long base = (long)blockIdx.x * 2048;   // 2048 float4 = 32 KB per array per block

    fvec4 x[8], y[8];
    long idx[8];
    #pragma unroll
    for (int k = 0; k < 8; ++k) {
        idx[k] = base + 256 * k + t;
        x[k] = (fvec4){0, 0, 0, 0};
        y[k] = (fvec4){0, 0, 0, 0};
    }

    // straight-line nontemporal loads: 16 independent global_load_dwordx4 (nt)
    #pragma unroll
    for (int k = 0; k < 8; ++k)
        if (idx[k] < n4) x[k] = __builtin_nontemporal_load(&a4[idx[k]]);
    #pragma unroll
    for (int k = 0; k < 8; ++k)
        if (idx[k] < n4) y[k] = __builtin_nontemporal_load(&b4[idx[k]]);

    float acc = 0.0f;
    #pragma unroll
    for (int k = 0; k < 8; ++k) {
        float d0 = x[k].x - y[k].x;
        float d1 = x[k].y - y[k].y;
        float d2 = x[k].z - y[k].z;
        float d3 = x[k].w - y[k].w;
        acc += d0 * d0 + d1 * d1 + d2 * d2 + d3 * d3;
    }

    // wave-64 shuffle reduction
    #pragma unroll
    for (int off = 32; off > 0; off >>= 1)
        acc += __shfl_down(acc, off, 64);

    __shared__ float wave_sums[4];
    const int lane = t & 63;
    const int wid  = t >> 6;
    if (lane == 0) wave_sums[wid] = acc;
    __syncthreads();

    if (t == 0)
        partial[blockIdx.x] = wave_sums[0] + wave_sums[1] + wave_sums[2] + wave_sums[3];
}

__global__ __launch_bounds__(256) void mse_stage2(const float* __restrict__ partial,
                                                  float* __restrict__ out,
                                                  int m) {
    float acc = 0.0f;
    for (int i = threadIdx.x; i < m; i += 256)
        acc += partial[i];

    #pragma unroll
    for (int off = 32; off > 0; off >>= 1)
        acc += __shfl_down(acc, off, 64);

    __shared__ float wave_sums[4];
    const int lane = threadIdx.x & 63;
    const int wid  = threadIdx.x >> 6;
    if (lane == 0) wave_sums[wid] = acc;
    __syncthreads();

    if (threadIdx.x == 0)
        out[0] = 0.5f * (wave_sums[0] + wave_sums[1] + wave_sums[2] + wave_sums[3]);
}

extern "C" void kernel_launch(void* const* d_in, const int* in_sizes, int n_in,
                              void* d_out, int out_size, void* d_ws, size_t ws_size,
                              hipStream_t stream) {
    const fvec4* a4 = (const fvec4*)d_in[0];
    const fvec4* b4 = (const fvec4*)d_in[1];
    float* out = (float*)d_out;
    float* partial = (float*)d_ws;

    const long n = (long)in_sizes[0];        // 40,000,000
    const long n4 = n >> 2;                  // 10,000,000 float4 groups (n % 4 == 0)
    const int blocks = (int)((n4 + 2047) / 2048);   // 4883 one-shot blocks

    mse_stage1<<<blocks, 256, 0, stream>>>(a4, b4, partial, n4);
    mse_stage2<<<1, 256, 0, stream>>>(partial, out, blocks);
}